// Round 3
// baseline (250.281 us; speedup 1.0000x reference)
//
#include <hip/hip_runtime.h>
#include <math.h>

// ClassMamba collapses: output = [upd_cls, patch(unchanged)].
// upd_cls depends only on token 0 (causal conv + scan from h0=0); A_log dead.
// Round 3: fused kernel, 1024 blocks. Blocks 0..31 run the 5-stage GEMV chain
// with sub-grid barriers (RELAXED polling + single acquire — round 2's
// per-poll ACQUIRE was an agent-scope L2-invalidation storm); blocks 32..1023
// stream the 67 MB copy concurrently with high MLP.

#define B_SZ 4
#define DIM 512
#define D_INNER 1024
#define L_TOK 4097
#define TOK_STRIDE (L_TOK * DIM)   // floats per batch
#define PB4 (TOK_STRIDE / 4)       // 524416 float4 per batch
#define DT_RANK 32
#define D_STATE 16
#define NCHAIN 32
#define NBLOCK 1024
#define NTHR 256

__device__ __forceinline__ float silu_f(float v) { return v / (1.f + expf(-v)); }

__device__ __forceinline__ float dot512(const float4* __restrict__ a,
                                        const float4* __restrict__ b) {
    float acc = 0.f;
#pragma unroll 8
    for (int k = 0; k < 128; ++k) {
        float4 x = a[k], y = b[k];
        acc += x.x * y.x + x.y * y.y + x.z * y.z + x.w * y.w;
    }
    return acc;
}

__device__ __forceinline__ float dot1024(const float4* __restrict__ a,
                                         const float4* __restrict__ b) {
    float acc = 0.f;
#pragma unroll 8
    for (int k = 0; k < 256; ++k) {
        float4 x = a[k], y = b[k];
        acc += x.x * y.x + x.y * y.y + x.z * y.z + x.w * y.w;
    }
    return acc;
}

// barrier among the NCHAIN chain blocks; ctr[phase] pre-zeroed by k_init.
// RELAXED polling (no per-poll cache op) + ONE acquire after exit.
__device__ __forceinline__ void chain_barrier(unsigned* ctr, int phase) {
    __syncthreads();
    if (threadIdx.x == 0) {
        __hip_atomic_fetch_add(&ctr[phase], 1u, __ATOMIC_RELEASE,
                               __HIP_MEMORY_SCOPE_AGENT);
        while (__hip_atomic_load(&ctr[phase], __ATOMIC_RELAXED,
                                 __HIP_MEMORY_SCOPE_AGENT) < (unsigned)NCHAIN) {
            __builtin_amdgcn_s_sleep(2);
        }
        (void)__hip_atomic_load(&ctr[phase], __ATOMIC_ACQUIRE,
                                __HIP_MEMORY_SCOPE_AGENT);
    }
    __syncthreads();
}

__global__ void k_init(unsigned* __restrict__ ctr) {
    if (threadIdx.x < 8) ctr[threadIdx.x] = 0u;
}

__global__ void __launch_bounds__(NTHR, 1)
k_fused(const float* __restrict__ x, const float* __restrict__ q_w,
        const float* __restrict__ in_proj_w, const float* __restrict__ conv_w,
        const float* __restrict__ conv_b, const float* __restrict__ x_proj_w,
        const float* __restrict__ dt_w, const float* __restrict__ dt_b,
        const float* __restrict__ Dp, const float* __restrict__ out_proj_w,
        const float* __restrict__ proj_w, const float* __restrict__ proj_b,
        float* __restrict__ out, float* __restrict__ ws, unsigned* __restrict__ ctr) {
    const int blk = blockIdx.x;
    const int tid = threadIdx.x;

    float* q_ws  = ws;           // 2048
    float* xs_ws = ws + 2048;    // 4096
    float* sz_ws = ws + 6144;    // 4096
    float* yy_ws = ws + 10240;   // 4096
    float* o_ws  = ws + 14336;   // 2048

    if (blk >= NCHAIN) {
        // ---------------- copy path: out[:] = x[:] except the 4 cls rows ----
        const float4* x4 = (const float4*)x;
        float4* o4 = (float4*)out;
        const unsigned stride = (NBLOCK - NCHAIN) * NTHR;  // 253952
        const unsigned n4 = (unsigned)(B_SZ * PB4);        // 2097664
        for (unsigned i = (unsigned)(blk - NCHAIN) * NTHR + tid; i < n4; i += stride) {
            unsigned r = i;
            if (r >= 2u * PB4) r -= 2u * PB4;
            if (r >= (unsigned)PB4) r -= (unsigned)PB4;
            if (r >= 128u) o4[i] = x4[i];  // skip float4 idx 0..127 of each batch
        }
        return;
    }

    // ---------------- chain path: blocks 0..31, 8192 threads --------------
    const int gt = blk * NTHR + tid;  // 0..8191

    // stage 1: q[b,d] = dot(cls[b], q_w[d])    (2048 threads)
    if (gt < B_SZ * DIM) {
        int b = gt >> 9, d = gt & 511;
        const float4* cls = (const float4*)(x + (size_t)b * TOK_STRIDE);
        q_ws[b * DIM + d] = dot512((const float4*)(q_w + (size_t)d * DIM), cls);
    }
    chain_barrier(ctr, 0);

    // stage 2: xz row + conv tap/silu          (8192 threads)
    {
        int b = gt >> 11, j = gt & 2047;
        float acc = dot512((const float4*)(in_proj_w + (size_t)j * DIM),
                           (const float4*)(q_ws + b * DIM));
        if (j < D_INNER)
            xs_ws[b * D_INNER + j] = silu_f(acc * conv_w[j * 4 + 3] + conv_b[j]);
        else
            sz_ws[b * D_INNER + (j - D_INNER)] = silu_f(acc);
    }
    chain_barrier(ctr, 1);

    // stage 3: x_dbl (redundant per block) + delta + scan@t0 + gate
    // blocks 0..15: block bb -> b = bb>>2, d = (bb&3)*256 + tid
    if (blk < 16) {
        __shared__ float part[64][5];
        __shared__ float xds[64];
        int b = blk >> 2;
        const float* xsb = xs_ws + b * D_INNER;
        int r = tid >> 2, p = tid & 3;
        {
            const float4* w = (const float4*)(x_proj_w + r * D_INNER + p * 256);
            const float4* v = (const float4*)(xsb + p * 256);
            float acc = 0.f;
#pragma unroll 8
            for (int k = 0; k < 64; ++k) {
                float4 wv = w[k], cv = v[k];
                acc += wv.x * cv.x + wv.y * cv.y + wv.z * cv.z + wv.w * cv.w;
            }
            part[r][p] = acc;
        }
        __syncthreads();
        if (tid < 64) xds[tid] = part[tid][0] + part[tid][1] + part[tid][2] + part[tid][3];
        __syncthreads();

        float S = 0.f;
#pragma unroll
        for (int n = 0; n < D_STATE; ++n) S += xds[32 + n] * xds[48 + n];
        int d = (blk & 3) * 256 + tid;
        float dp = dt_b[d];
        const float4* dw = (const float4*)(dt_w + d * DT_RANK);
#pragma unroll
        for (int rr = 0; rr < 8; ++rr) {
            float4 wv = dw[rr];
            dp += xds[rr * 4] * wv.x + xds[rr * 4 + 1] * wv.y +
                  xds[rr * 4 + 2] * wv.z + xds[rr * 4 + 3] * wv.w;
        }
        float delta = (dp > 20.f) ? dp : log1pf(expf(dp));
        float u = xsb[d];
        yy_ws[b * D_INNER + d] = u * (delta * S + Dp[d]) * sz_ws[b * D_INNER + d];
    }
    chain_barrier(ctr, 2);

    // stage 4: o[b,i] = dot(yy[b], out_proj_w[i])   (2048 threads)
    if (gt < B_SZ * DIM) {
        int b = gt >> 9, i = gt & 511;
        o_ws[b * DIM + i] = dot1024((const float4*)(out_proj_w + (size_t)i * D_INNER),
                                    (const float4*)(yy_ws + b * D_INNER));
    }
    chain_barrier(ctr, 3);

    // stage 5: upd[b,j] -> out token 0              (2048 threads)
    if (gt < B_SZ * DIM) {
        int b = gt >> 9, j = gt & 511;
        float acc = proj_b[j] + dot512((const float4*)(proj_w + (size_t)j * DIM),
                                       (const float4*)(o_ws + b * DIM));
        out[(size_t)b * TOK_STRIDE + j] = acc;
    }
}

extern "C" void kernel_launch(void* const* d_in, const int* in_sizes, int n_in,
                              void* d_out, int out_size, void* d_ws, size_t ws_size,
                              hipStream_t stream) {
    const float* x          = (const float*)d_in[0];
    const float* q_w        = (const float*)d_in[1];
    const float* in_proj_w  = (const float*)d_in[2];
    const float* conv_w     = (const float*)d_in[3];
    const float* conv_b     = (const float*)d_in[4];
    const float* x_proj_w   = (const float*)d_in[5];
    const float* dt_w       = (const float*)d_in[6];
    const float* dt_b       = (const float*)d_in[7];
    // d_in[8] = A_log: unused (h0 = 0)
    const float* Dp         = (const float*)d_in[9];
    const float* out_proj_w = (const float*)d_in[10];
    const float* proj_w     = (const float*)d_in[11];
    const float* proj_b     = (const float*)d_in[12];
    float* out = (float*)d_out;
    float* ws  = (float*)d_ws;
    unsigned* ctr = (unsigned*)(ws + 18432);

    k_init<<<1, 64, 0, stream>>>(ctr);
    k_fused<<<NBLOCK, NTHR, 0, stream>>>(x, q_w, in_proj_w, conv_w, conv_b,
                                         x_proj_w, dt_w, dt_b, Dp, out_proj_w,
                                         proj_w, proj_b, out, ws, ctr);
}

// Round 4
// 199.650 us; speedup vs baseline: 1.2536x; 1.2536x over previous
//
#include <hip/hip_runtime.h>
#include <math.h>

// ClassMamba collapses: output = [upd_cls, patch(unchanged)].
// upd_cls depends only on token 0 (causal conv + scan from h0=0); A_log dead.
// Round 4: ZERO cross-block sync. Blocks 0..3: one block per batch element
// runs the whole 5-stage GEMV chain in-block (LDS + __syncthreads only).
// Blocks 4..255 stream the 33.5 MB copy concurrently. No ws, no atomics.

#define B_SZ 4
#define DIM 512
#define D_INNER 1024
#define L_TOK 4097
#define TOK_STRIDE (L_TOK * DIM)   // floats per batch
#define PB4 (TOK_STRIDE / 4)       // 524416 float4 per batch
#define DT_RANK 32
#define D_STATE 16
#define NBLOCK 256
#define NTHR 1024

__device__ __forceinline__ float silu_f(float v) { return v / (1.f + expf(-v)); }

__device__ __forceinline__ float red16(float v) {
    v += __shfl_xor(v, 1, 64);
    v += __shfl_xor(v, 2, 64);
    v += __shfl_xor(v, 4, 64);
    v += __shfl_xor(v, 8, 64);
    return v;
}
__device__ __forceinline__ float red32(float v) {
    v = red16(v);
    v += __shfl_xor(v, 16, 64);
    return v;
}

__device__ __forceinline__ float f4dot(float4 a, float4 b) {
    return a.x * b.x + a.y * b.y + a.z * b.z + a.w * b.w;
}

__global__ void __launch_bounds__(NTHR, 4)
k_fused(const float* __restrict__ x, const float* __restrict__ q_w,
        const float* __restrict__ in_proj_w, const float* __restrict__ conv_w,
        const float* __restrict__ conv_b, const float* __restrict__ x_proj_w,
        const float* __restrict__ dt_w, const float* __restrict__ dt_b,
        const float* __restrict__ Dp, const float* __restrict__ out_proj_w,
        const float* __restrict__ proj_w, const float* __restrict__ proj_b,
        float* __restrict__ out) {
    const int blk = blockIdx.x;
    const int tid = threadIdx.x;

    if (blk >= B_SZ) {
        // ---------------- copy path: out[:] = x[:] except the 4 cls rows ----
        const float4* x4 = (const float4*)x;
        float4* o4 = (float4*)out;
        const unsigned stride = (NBLOCK - B_SZ) * NTHR;  // 258048
        const unsigned n4 = (unsigned)(B_SZ * PB4);      // 2097664
        for (unsigned i = (unsigned)(blk - B_SZ) * NTHR + tid; i < n4; i += stride) {
            unsigned r = i;
            if (r >= 2u * PB4) r -= 2u * PB4;
            if (r >= (unsigned)PB4) r -= (unsigned)PB4;
            if (r >= 128u) o4[i] = x4[i];  // skip float4 idx 0..127 of each batch
        }
        return;
    }

    // ---------------- chain path: block b handles batch element b ----------
    const int b = blk;
    const int w = tid >> 6;        // wave 0..15
    const int lane = tid & 63;
    const int c = lane & 15, g = lane >> 4;    // 16-lane groups (rows of 512)
    const int c2 = lane & 31, g2 = lane >> 5;  // 32-lane groups (rows of 1024)

    __shared__ float q_lds[DIM];        // 2 KB
    __shared__ float raw_lds[2048];     // 8 KB
    __shared__ float xs_lds[D_INNER];   // 4 KB
    __shared__ float gz_lds[D_INNER];   // 4 KB
    __shared__ float xd_lds[64];
    __shared__ float y_lds[D_INNER];    // 4 KB
    __shared__ float o_lds[DIM];        // 2 KB

    // ---- S1: q[r] = dot(cls, q_w[r,:])  (512 rows of 512) ----
    {
        const float4* xc = (const float4*)(x + (size_t)b * TOK_STRIDE);
        float4 cv[8];
#pragma unroll
        for (int j = 0; j < 8; ++j) cv[j] = xc[c + 16 * j];
#pragma unroll 2
        for (int p = 0; p < 8; ++p) {
            int r = w * 32 + p * 4 + g;
            const float4* wr = (const float4*)(q_w + (size_t)r * DIM);
            float acc = 0.f;
#pragma unroll
            for (int j = 0; j < 8; ++j) acc += f4dot(wr[c + 16 * j], cv[j]);
            acc = red16(acc);
            if (c == 0) q_lds[r] = acc;
        }
    }
    __syncthreads();

    // ---- S2: raw[r] = dot(q, in_proj_w[r,:])  (2048 rows of 512) ----
    {
        const float4* qv4 = (const float4*)q_lds;
        float4 qv[8];
#pragma unroll
        for (int j = 0; j < 8; ++j) qv[j] = qv4[c + 16 * j];
#pragma unroll 2
        for (int p = 0; p < 32; ++p) {
            int r = w * 128 + p * 4 + g;
            const float4* wr = (const float4*)(in_proj_w + (size_t)r * DIM);
            float acc = 0.f;
#pragma unroll
            for (int j = 0; j < 8; ++j) acc += f4dot(wr[c + 16 * j], qv[j]);
            acc = red16(acc);
            if (c == 0) raw_lds[r] = acc;
        }
    }
    __syncthreads();

    // ---- S2post: conv tap + silu on both halves ----
    {
        int d = tid;  // 0..1023
        float xi = raw_lds[d];
        float z  = raw_lds[d + 1024];
        xs_lds[d] = silu_f(xi * conv_w[d * 4 + 3] + conv_b[d]);
        gz_lds[d] = silu_f(z);
    }
    __syncthreads();

    // ---- S3: xd[r] = dot(xs, x_proj_w[r,:])  (64 rows of 1024) ----
    {
        const float4* xv4 = (const float4*)xs_lds;
        float4 xv[8];
#pragma unroll
        for (int j = 0; j < 8; ++j) xv[j] = xv4[c2 + 32 * j];
#pragma unroll
        for (int p = 0; p < 2; ++p) {
            int r = w * 4 + p * 2 + g2;
            const float4* wr = (const float4*)(x_proj_w + (size_t)r * D_INNER);
            float acc = 0.f;
#pragma unroll
            for (int j = 0; j < 8; ++j) acc += f4dot(wr[c2 + 32 * j], xv[j]);
            acc = red32(acc);
            if (c2 == 0) xd_lds[r] = acc;
        }
    }
    __syncthreads();

    // ---- delta + scan@t0 + gate -> y ----
    {
        int d = tid;
        float S = 0.f;
#pragma unroll
        for (int n = 0; n < D_STATE; ++n) S += xd_lds[32 + n] * xd_lds[48 + n];
        float dp = dt_b[d];
        const float4* dw = (const float4*)(dt_w + (size_t)d * DT_RANK);
#pragma unroll
        for (int rr = 0; rr < 8; ++rr) {
            float4 wv = dw[rr];
            dp += xd_lds[rr * 4] * wv.x + xd_lds[rr * 4 + 1] * wv.y +
                  xd_lds[rr * 4 + 2] * wv.z + xd_lds[rr * 4 + 3] * wv.w;
        }
        float delta = (dp > 20.f) ? dp : log1pf(expf(dp));
        y_lds[d] = xs_lds[d] * (delta * S + Dp[d]) * gz_lds[d];
    }
    __syncthreads();

    // ---- S4: o[r] = dot(y, out_proj_w[r,:])  (512 rows of 1024) ----
    {
        const float4* yv4 = (const float4*)y_lds;
        float4 yv[8];
#pragma unroll
        for (int j = 0; j < 8; ++j) yv[j] = yv4[c2 + 32 * j];
#pragma unroll 2
        for (int p = 0; p < 16; ++p) {
            int r = w * 32 + p * 2 + g2;
            const float4* wr = (const float4*)(out_proj_w + (size_t)r * D_INNER);
            float acc = 0.f;
#pragma unroll
            for (int j = 0; j < 8; ++j) acc += f4dot(wr[c2 + 32 * j], yv[j]);
            acc = red32(acc);
            if (c2 == 0) o_lds[r] = acc;
        }
    }
    __syncthreads();

    // ---- S5: upd[r] = dot(o, proj_w[r,:]) + proj_b[r] -> out token 0 ----
    {
        const float4* ov4 = (const float4*)o_lds;
        float4 ov[8];
#pragma unroll
        for (int j = 0; j < 8; ++j) ov[j] = ov4[c + 16 * j];
#pragma unroll 2
        for (int p = 0; p < 8; ++p) {
            int r = w * 32 + p * 4 + g;
            const float4* wr = (const float4*)(proj_w + (size_t)r * DIM);
            float acc = 0.f;
#pragma unroll
            for (int j = 0; j < 8; ++j) acc += f4dot(wr[c + 16 * j], ov[j]);
            acc = red16(acc);
            if (c == 0) out[(size_t)b * TOK_STRIDE + r] = acc + proj_b[r];
        }
    }
}

extern "C" void kernel_launch(void* const* d_in, const int* in_sizes, int n_in,
                              void* d_out, int out_size, void* d_ws, size_t ws_size,
                              hipStream_t stream) {
    const float* x          = (const float*)d_in[0];
    const float* q_w        = (const float*)d_in[1];
    const float* in_proj_w  = (const float*)d_in[2];
    const float* conv_w     = (const float*)d_in[3];
    const float* conv_b     = (const float*)d_in[4];
    const float* x_proj_w   = (const float*)d_in[5];
    const float* dt_w       = (const float*)d_in[6];
    const float* dt_b       = (const float*)d_in[7];
    // d_in[8] = A_log: unused (h0 = 0)
    const float* Dp         = (const float*)d_in[9];
    const float* out_proj_w = (const float*)d_in[10];
    const float* proj_w     = (const float*)d_in[11];
    const float* proj_b     = (const float*)d_in[12];
    float* out = (float*)d_out;

    k_fused<<<NBLOCK, NTHR, 0, stream>>>(x, q_w, in_proj_w, conv_w, conv_b,
                                         x_proj_w, dt_w, dt_b, Dp, out_proj_w,
                                         proj_w, proj_b, out);
}

// Round 5
// 146.786 us; speedup vs baseline: 1.7051x; 1.3601x over previous
//
#include <hip/hip_runtime.h>
#include <math.h>

// ClassMamba collapses: output = [upd_cls, patch(unchanged)].
// upd_cls depends only on token 0 (causal conv + scan from h0=0); A_log dead.
// Round 5: 5 stage kernels (kernel boundary = the only cheap global barrier).
// Each stage spreads its weight matrix across 8-32 blocks and dots every
// weight row against ALL 4 batch vectors (LDS-staged, 4 acc/lane) -> weight
// bytes read once, ~128 KB/CU max (round 4 showed ~60 GB/s/CU L3 ceiling when
// one CU pulls all 8.5 MB). The 67 MB copy is sliced across the 5 kernels.

#define B_SZ 4
#define DIM 512
#define D_INNER 1024
#define L_TOK 4097
#define TOK_STRIDE (L_TOK * DIM)
#define PB4 (TOK_STRIDE / 4)       // 524416 float4 per batch
#define N4 (B_SZ * PB4)            // 2097664
#define DT_RANK 32
#define D_STATE 16
#define CB 1639                    // copy blocks per kernel

// copy slice boundaries (float4 indices)
#define SL0 0u
#define SL1 419533u
#define SL2 839066u
#define SL3 1258599u
#define SL4 1678132u
#define SL5 2097664u

__device__ __forceinline__ float silu_f(float v) { return v / (1.f + expf(-v)); }
__device__ __forceinline__ float f4dot(float4 a, float4 b) {
    return a.x * b.x + a.y * b.y + a.z * b.z + a.w * b.w;
}
__device__ __forceinline__ float red16(float v) {
    v += __shfl_xor(v, 1, 64); v += __shfl_xor(v, 2, 64);
    v += __shfl_xor(v, 4, 64); v += __shfl_xor(v, 8, 64);
    return v;
}
__device__ __forceinline__ float red32(float v) {
    v = red16(v); v += __shfl_xor(v, 16, 64); return v;
}
__device__ __forceinline__ float sel4(int c, float a0, float a1, float a2, float a3) {
    return (c == 0) ? a0 : (c == 1) ? a1 : (c == 2) ? a2 : a3;
}

// copy slice [beg,end) of out[:] = x[:], skipping the 4 cls rows
__device__ __forceinline__ void do_copy(const float4* __restrict__ x4,
                                        float4* __restrict__ o4,
                                        int cb_idx, unsigned beg, unsigned end) {
    const unsigned stride = (unsigned)CB * 256u;
    for (unsigned i = beg + (unsigned)cb_idx * 256u + threadIdx.x; i < end; i += stride) {
        unsigned r = i;
        if (r >= 2u * PB4) r -= 2u * PB4;
        if (r >= (unsigned)PB4) r -= (unsigned)PB4;
        if (r >= 128u) o4[i] = x4[i];
    }
}

// ---- k1: q[b,r] = dot(cls[b], q_w[r,:])   8 chain blocks ----
__global__ void __launch_bounds__(256)
k1_q(const float* __restrict__ x, const float* __restrict__ q_w,
     float* __restrict__ q_ws, float4* __restrict__ o4) {
    const int blk = blockIdx.x, tid = threadIdx.x;
    if (blk >= 8) { do_copy((const float4*)x, o4, blk - 8, SL0, SL1); return; }
    __shared__ float cls[4 * DIM];
    {
        float4* cl4 = (float4*)cls;
        const float4* xg = (const float4*)x;
#pragma unroll
        for (int t = 0; t < 2; ++t) {
            int f = tid + t * 256;                 // 0..511
            cl4[f] = xg[(size_t)(f >> 7) * PB4 + (f & 127)];
        }
    }
    __syncthreads();
    const int w = tid >> 6, lane = tid & 63, c = lane & 15, g = lane >> 4;
#pragma unroll
    for (int p = 0; p < 4; ++p) {
        int r = blk * 64 + w * 16 + p * 4 + g;
        const float4* wr = (const float4*)(q_w + (size_t)r * DIM);
        float a0 = 0, a1 = 0, a2 = 0, a3 = 0;
#pragma unroll
        for (int j = 0; j < 8; ++j) {
            float4 wv = wr[c + 16 * j];
            a0 += f4dot(wv, ((const float4*)(cls))[c + 16 * j]);
            a1 += f4dot(wv, ((const float4*)(cls + DIM))[c + 16 * j]);
            a2 += f4dot(wv, ((const float4*)(cls + 2 * DIM))[c + 16 * j]);
            a3 += f4dot(wv, ((const float4*)(cls + 3 * DIM))[c + 16 * j]);
        }
        a0 = red16(a0); a1 = red16(a1); a2 = red16(a2); a3 = red16(a3);
        if (c < 4) q_ws[c * DIM + r] = sel4(c, a0, a1, a2, a3);
    }
}

// ---- k2: raw[b,r] = dot(q[b], in_proj_w[r,:]); conv tap + silu   32 blocks ----
__global__ void __launch_bounds__(256)
k2_xz(const float* __restrict__ q_ws, const float* __restrict__ in_proj_w,
      const float* __restrict__ conv_w, const float* __restrict__ conv_b,
      float* __restrict__ xs_ws, float* __restrict__ gz_ws,
      const float4* __restrict__ x4, float4* __restrict__ o4) {
    const int blk = blockIdx.x, tid = threadIdx.x;
    if (blk >= 32) { do_copy(x4, o4, blk - 32, SL1, SL2); return; }
    __shared__ float q_lds[4 * DIM];
    {
        float4* ql = (float4*)q_lds;
        const float4* qg = (const float4*)q_ws;
        ql[tid] = qg[tid]; ql[tid + 256] = qg[tid + 256];
    }
    __syncthreads();
    const int w = tid >> 6, lane = tid & 63, c = lane & 15, g = lane >> 4;
#pragma unroll
    for (int p = 0; p < 4; ++p) {
        int r = blk * 64 + w * 16 + p * 4 + g;   // 0..2047
        const float4* wr = (const float4*)(in_proj_w + (size_t)r * DIM);
        float a0 = 0, a1 = 0, a2 = 0, a3 = 0;
#pragma unroll
        for (int j = 0; j < 8; ++j) {
            float4 wv = wr[c + 16 * j];
            a0 += f4dot(wv, ((const float4*)(q_lds))[c + 16 * j]);
            a1 += f4dot(wv, ((const float4*)(q_lds + DIM))[c + 16 * j]);
            a2 += f4dot(wv, ((const float4*)(q_lds + 2 * DIM))[c + 16 * j]);
            a3 += f4dot(wv, ((const float4*)(q_lds + 3 * DIM))[c + 16 * j]);
        }
        a0 = red16(a0); a1 = red16(a1); a2 = red16(a2); a3 = red16(a3);
        if (c < 4) {
            float v = sel4(c, a0, a1, a2, a3);
            if (r < D_INNER)
                xs_ws[c * D_INNER + r] = silu_f(v * conv_w[r * 4 + 3] + conv_b[r]);
            else
                gz_ws[c * D_INNER + (r - D_INNER)] = silu_f(v);
        }
    }
}

// ---- k3: xd[b,r] = dot(xs[b], x_proj_w[r,:])  (64 rows)   4 blocks ----
__global__ void __launch_bounds__(256)
k3_xd(const float* __restrict__ xs_ws, const float* __restrict__ x_proj_w,
      float* __restrict__ xd_ws, const float4* __restrict__ x4,
      float4* __restrict__ o4) {
    const int blk = blockIdx.x, tid = threadIdx.x;
    if (blk >= 4) { do_copy(x4, o4, blk - 4, SL2, SL3); return; }
    __shared__ float xs_lds[4 * D_INNER];   // 16 KB
    {
        float4* xl = (float4*)xs_lds;
        const float4* xg = (const float4*)xs_ws;
#pragma unroll
        for (int t = 0; t < 4; ++t) xl[tid + t * 256] = xg[tid + t * 256];
    }
    __syncthreads();
    const int w = tid >> 6, lane = tid & 63, c2 = lane & 31, g2 = lane >> 5;
#pragma unroll
    for (int p = 0; p < 2; ++p) {
        int r = blk * 16 + w * 4 + p * 2 + g2;   // 0..63
        const float4* wr = (const float4*)(x_proj_w + (size_t)r * D_INNER);
        float a0 = 0, a1 = 0, a2 = 0, a3 = 0;
#pragma unroll
        for (int j = 0; j < 8; ++j) {
            float4 wv = wr[c2 + 32 * j];
            a0 += f4dot(wv, ((const float4*)(xs_lds))[c2 + 32 * j]);
            a1 += f4dot(wv, ((const float4*)(xs_lds + D_INNER))[c2 + 32 * j]);
            a2 += f4dot(wv, ((const float4*)(xs_lds + 2 * D_INNER))[c2 + 32 * j]);
            a3 += f4dot(wv, ((const float4*)(xs_lds + 3 * D_INNER))[c2 + 32 * j]);
        }
        a0 = red32(a0); a1 = red32(a1); a2 = red32(a2); a3 = red32(a3);
        if (c2 < 4) xd_ws[c2 * 64 + r] = sel4(c2, a0, a1, a2, a3);
    }
}

// ---- k4: build y (delta+scan@t0+gate), then o[b,r] = dot(y[b], out_proj_w[r,:])  16 blocks ----
__global__ void __launch_bounds__(256)
k4_out(const float* __restrict__ xs_ws, const float* __restrict__ gz_ws,
       const float* __restrict__ xd_ws, const float* __restrict__ dt_w,
       const float* __restrict__ dt_b, const float* __restrict__ Dp,
       const float* __restrict__ out_proj_w, float* __restrict__ o_ws,
       const float4* __restrict__ x4, float4* __restrict__ o4) {
    const int blk = blockIdx.x, tid = threadIdx.x;
    if (blk >= 16) { do_copy(x4, o4, blk - 16, SL3, SL4); return; }
    __shared__ float xd_lds[4 * 64];        // 1 KB
    __shared__ float y_lds[4 * D_INNER];    // 16 KB
    if (tid < 64) ((float4*)xd_lds)[tid] = ((const float4*)xd_ws)[tid];
    __syncthreads();
    float S[4];
#pragma unroll
    for (int b = 0; b < 4; ++b) {
        float s = 0.f;
#pragma unroll
        for (int n = 0; n < D_STATE; ++n)
            s += xd_lds[b * 64 + 32 + n] * xd_lds[b * 64 + 48 + n];
        S[b] = s;
    }
#pragma unroll
    for (int qq = 0; qq < 4; ++qq) {
        int d = tid + qq * 256;
        const float4* dw = (const float4*)(dt_w + (size_t)d * DT_RANK);
        float4 dwv[8];
#pragma unroll
        for (int j = 0; j < 8; ++j) dwv[j] = dw[j];
        float Dd = Dp[d], db = dt_b[d];
#pragma unroll
        for (int b = 0; b < 4; ++b) {
            const float4* xd4 = (const float4*)(xd_lds + b * 64);
            float dp = db;
#pragma unroll
            for (int j = 0; j < 8; ++j) dp += f4dot(dwv[j], xd4[j]);
            float delta = (dp > 20.f) ? dp : log1pf(expf(dp));
            y_lds[b * D_INNER + d] =
                xs_ws[b * D_INNER + d] * (delta * S[b] + Dd) * gz_ws[b * D_INNER + d];
        }
    }
    __syncthreads();
    const int w = tid >> 6, lane = tid & 63, c2 = lane & 31, g2 = lane >> 5;
#pragma unroll
    for (int p = 0; p < 4; ++p) {
        int r = blk * 32 + w * 8 + p * 2 + g2;   // 0..511
        const float4* wr = (const float4*)(out_proj_w + (size_t)r * D_INNER);
        float a0 = 0, a1 = 0, a2 = 0, a3 = 0;
#pragma unroll
        for (int j = 0; j < 8; ++j) {
            float4 wv = wr[c2 + 32 * j];
            a0 += f4dot(wv, ((const float4*)(y_lds))[c2 + 32 * j]);
            a1 += f4dot(wv, ((const float4*)(y_lds + D_INNER))[c2 + 32 * j]);
            a2 += f4dot(wv, ((const float4*)(y_lds + 2 * D_INNER))[c2 + 32 * j]);
            a3 += f4dot(wv, ((const float4*)(y_lds + 3 * D_INNER))[c2 + 32 * j]);
        }
        a0 = red32(a0); a1 = red32(a1); a2 = red32(a2); a3 = red32(a3);
        if (c2 < 4) o_ws[c2 * DIM + r] = sel4(c2, a0, a1, a2, a3);
    }
}

// ---- k5: upd[b,r] = dot(o[b], proj_w[r,:]) + proj_b[r] -> out token 0   8 blocks ----
__global__ void __launch_bounds__(256)
k5_upd(const float* __restrict__ o_ws, const float* __restrict__ proj_w,
       const float* __restrict__ proj_b, float* __restrict__ out,
       const float4* __restrict__ x4, float4* __restrict__ o4) {
    const int blk = blockIdx.x, tid = threadIdx.x;
    if (blk >= 8) { do_copy(x4, o4, blk - 8, SL4, SL5); return; }
    __shared__ float o_lds[4 * DIM];
    {
        float4* ol = (float4*)o_lds;
        const float4* og = (const float4*)o_ws;
        ol[tid] = og[tid]; ol[tid + 256] = og[tid + 256];
    }
    __syncthreads();
    const int w = tid >> 6, lane = tid & 63, c = lane & 15, g = lane >> 4;
#pragma unroll
    for (int p = 0; p < 4; ++p) {
        int r = blk * 64 + w * 16 + p * 4 + g;
        const float4* wr = (const float4*)(proj_w + (size_t)r * DIM);
        float a0 = 0, a1 = 0, a2 = 0, a3 = 0;
#pragma unroll
        for (int j = 0; j < 8; ++j) {
            float4 wv = wr[c + 16 * j];
            a0 += f4dot(wv, ((const float4*)(o_lds))[c + 16 * j]);
            a1 += f4dot(wv, ((const float4*)(o_lds + DIM))[c + 16 * j]);
            a2 += f4dot(wv, ((const float4*)(o_lds + 2 * DIM))[c + 16 * j]);
            a3 += f4dot(wv, ((const float4*)(o_lds + 3 * DIM))[c + 16 * j]);
        }
        a0 = red16(a0); a1 = red16(a1); a2 = red16(a2); a3 = red16(a3);
        if (c < 4) out[(size_t)c * TOK_STRIDE + r] = sel4(c, a0, a1, a2, a3) + proj_b[r];
    }
}

extern "C" void kernel_launch(void* const* d_in, const int* in_sizes, int n_in,
                              void* d_out, int out_size, void* d_ws, size_t ws_size,
                              hipStream_t stream) {
    const float* x          = (const float*)d_in[0];
    const float* q_w        = (const float*)d_in[1];
    const float* in_proj_w  = (const float*)d_in[2];
    const float* conv_w     = (const float*)d_in[3];
    const float* conv_b     = (const float*)d_in[4];
    const float* x_proj_w   = (const float*)d_in[5];
    const float* dt_w       = (const float*)d_in[6];
    const float* dt_b       = (const float*)d_in[7];
    // d_in[8] = A_log: unused (h0 = 0)
    const float* Dp         = (const float*)d_in[9];
    const float* out_proj_w = (const float*)d_in[10];
    const float* proj_w     = (const float*)d_in[11];
    const float* proj_b     = (const float*)d_in[12];
    float* out = (float*)d_out;
    float* ws  = (float*)d_ws;

    float* q_ws  = ws;          // 2048
    float* xs_ws = ws + 2048;   // 4096
    float* gz_ws = ws + 6144;   // 4096
    float* xd_ws = ws + 10240;  // 256
    float* o_ws  = ws + 10496;  // 2048

    const float4* x4 = (const float4*)x;
    float4* o4 = (float4*)out;

    k1_q  <<<8 + CB,  256, 0, stream>>>(x, q_w, q_ws, o4);
    k2_xz <<<32 + CB, 256, 0, stream>>>(q_ws, in_proj_w, conv_w, conv_b,
                                        xs_ws, gz_ws, x4, o4);
    k3_xd <<<4 + CB,  256, 0, stream>>>(xs_ws, x_proj_w, xd_ws, x4, o4);
    k4_out<<<16 + CB, 256, 0, stream>>>(xs_ws, gz_ws, xd_ws, dt_w, dt_b, Dp,
                                        out_proj_w, o_ws, x4, o4);
    k5_upd<<<8 + CB,  256, 0, stream>>>(o_ws, proj_w, proj_b, out, x4, o4);
}